// Round 13
// baseline (101.956 us; speedup 1.0000x reference)
//
#include <hip/hip_runtime.h>

// AdditiveSelfAttentionLayer: B=4, N=1024, D=64, fp32
// out[b,i,d] = sum_j softmax_j( sum_d' tanh(x[b,i,d']+x[b,j,d']) ) * x[b,j,d]
//
// Identities:
//   tanh(s) = 1 - 2/(1+e^{2s});  e_j = sum_d tanh = 64 - 2*rsum
//   a_d = e^{2s_d} = exp2(C*(xi_d+xj_d)), C = 2*log2(e)   (in-lane; no E array)
//   PAIR MERGE: 1/(1+a) + 1/(1+b) = (2+p)/(1+p+q),  p=a+b, q=ab  (native v2f pk ops)
//   softmax shift 32: w_j = exp(e_j - 32) = exp2(32*log2e - C*rsum_j)
//
// Round 13: R12 minus the asm pins, plus amdgpu_waves_per_eu(2,3).
// R8/R10/R12 post-mortems: launch_bounds only sets the register BUDGET; the
// allocator still TARGETS 6-8 waves/EU and remats (R8) or spills (R10/R12)
// to get there. waves_per_eu(2,3) caps the occupancy target at 3 waves/EU,
// removing the incentive: live set (acc 64 + xjs 64 + px 16 + temps ~= 165)
// fits the 3-wave budget (~170) with no spill and no remat.
// LDS per wave-tile: 16 b128 reads + 4 writes (vs R7's 40 ops).

#define NB 4
#define NN 1024
#define ND 64
#define TJ 64             // j-rows per LDS tile (lane = local j)
#define TI 4              // i-rows per WG = waves per WG
#define NTILES (NN / TJ)  // 16

#if __has_builtin(__builtin_amdgcn_exp2f)
#define EXP2F(x) __builtin_amdgcn_exp2f(x)
#else
#define EXP2F(x) exp2f(x)
#endif
#if __has_builtin(__builtin_amdgcn_rcpf)
#define RCPF(x) __builtin_amdgcn_rcpf(x)
#else
#define RCPF(x) (1.0f / (x))
#endif

static constexpr float C_SCALE = 2.8853900817779268f;   // 2*log2(e)
static constexpr float K_SHIFT = 46.166241308446828f;   // 32*log2(e)

typedef float v2f __attribute__((ext_vector_type(2)));

#define PKFMA(a, b, c) __builtin_elementwise_fma((a), (b), (c))

__device__ __forceinline__ v2f vlo(float4 v) { v2f r; r.x = v.x; r.y = v.y; return r; }
__device__ __forceinline__ v2f vhi(float4 v) { v2f r; r.x = v.z; r.y = v.w; return r; }

__global__ __attribute__((amdgpu_flat_work_group_size(256, 256),
                          amdgpu_waves_per_eu(2, 3)))
void addattn_kernel(const float* __restrict__ x, float* __restrict__ out) {
    __shared__ float x_lds[TJ * ND];   // 16 KB, XOR-swizzled at float4 grain

    const int tid   = threadIdx.x;
    const int lane  = tid & 63;
    const int wave  = tid >> 6;
    const int wg    = blockIdx.x;
    const int b     = wg >> 8;                       // 256 WGs per batch
    const int ibase = (wg & 255) * TI;
    // wave-uniform i-row index (forced into SGPR so xi loads become s_loads)
    const int i0    = __builtin_amdgcn_readfirstlane(ibase + wave);

    const float* xb  = x + (size_t)b * NN * ND;
    const float* xip = xb + (size_t)i0 * ND;         // uniform pointer

    // ---- tile-0 loads ----
    float4 px[4];
    {
        const float4* srcx = (const float4*)xb;
        #pragma unroll
        for (int it = 0; it < 4; ++it) px[it] = srcx[it * 256 + tid];
    }
    #pragma unroll
    for (int it = 0; it < 4; ++it) {
        int idx = it * 256 + tid;
        int j   = idx >> 4;         // 16 float4 per row
        int c   = idx & 15;
        *(float4*)&x_lds[j * ND + ((c ^ (j & 15)) << 2)] = px[it];
    }
    __syncthreads();

    v2f acc2[32];                       // out[i0] numerator, d-pairs, in-lane
    #pragma unroll
    for (int k = 0; k < 32; ++k) acc2[k] = (v2f){0.f, 0.f};
    float dn = 0.f;                     // per-lane denominator partial

    const v2f C2 = {C_SCALE, C_SCALE};

    for (int t = 0; t < NTILES; ++t) {
        // ---- prefetch tile t+1's x (16 VGPR; hides under compute) ----
        if (t + 1 < NTILES) {
            const float4* srcx = (const float4*)(xb + (size_t)(t + 1) * TJ * ND);
            #pragma unroll
            for (int it = 0; it < 4; ++it) px[it] = srcx[it * 256 + tid];
        }

        // ---- tanh phase: lane = local j; fused exp2; pair-merged packed rcp ----
        const int key = lane & 15;
        float4 xjs[16];                 // this lane's x row, retained for PV
        v2f rse = {0.f, 0.f}, rso = {0.f, 0.f};
        #pragma unroll
        for (int c = 0; c < 16; ++c) {
            float4 xq = *(const float4*)&x_lds[lane * ND + ((c ^ key) << 2)];
            xjs[c] = xq;
            float4 xiq = *(const float4*)&xip[c * 4];       // uniform s_load
            v2f Ul = C2 * (vlo(xq) + vlo(xiq));             // C*(xi+xj), d0,d1
            v2f Uh = C2 * (vhi(xq) + vhi(xiq));             // d2,d3
            v2f A, Q;
            A.x = EXP2F(Ul.x); A.y = EXP2F(Ul.y);           // e^{2s}, d0,d1
            Q.x = EXP2F(Uh.x); Q.y = EXP2F(Uh.y);           // e^{2s}, d2,d3
            v2f p = A + Q;
            v2f r = PKFMA(A, Q, p + 1.0f);                  // 1 + p + q
            v2f tt; tt.x = RCPF(r.x); tt.y = RCPF(r.y);
            if (c & 1) rso = PKFMA(p + 2.0f, tt, rso);
            else       rse = PKFMA(p + 2.0f, tt, rse);
        }
        v2f rs = rse + rso;
        float w = EXP2F(fmaf(-C_SCALE, rs.x + rs.y, K_SHIFT)); // = exp(e_j - 32)
        dn += w;
        v2f w2; w2.x = w; w2.y = w;

        // ---- PV phase: acc[d] += w * x[j=lane][d]  (from retained registers) ----
        #pragma unroll
        for (int c = 0; c < 16; ++c) {
            acc2[2 * c]     = PKFMA(w2, vlo(xjs[c]), acc2[2 * c]);
            acc2[2 * c + 1] = PKFMA(w2, vhi(xjs[c]), acc2[2 * c + 1]);
        }

        // ---- publish prefetched tile ----
        if (t + 1 < NTILES) {
            __syncthreads();   // all waves done reading tile t
            #pragma unroll
            for (int it = 0; it < 4; ++it) {
                int idx = it * 256 + tid;
                int j   = idx >> 4;
                int c   = idx & 15;
                *(float4*)&x_lds[j * ND + ((c ^ (j & 15)) << 2)] = px[it];
            }
            __syncthreads();   // publish tile t+1
        }
    }

    // ---- cross-lane transpose-reduction (round-1/7-verified butterfly) ----
    float* accf = (float*)acc2;
    #pragma unroll
    for (int s = 0; s < 6; ++s) {
        const int half = 32 >> s;
        const int sel  = (lane >> (5 - s)) & 1;
        #pragma unroll
        for (int k = 0; k < half; ++k) {
            float keep = sel ? accf[k + half] : accf[k];
            float send = sel ? accf[k] : accf[k + half];
            float recv = __shfl_xor(send, half, 64);
            accf[k] = keep + recv;
        }
    }
    #pragma unroll
    for (int s = 0; s < 6; ++s) dn += __shfl_xor(dn, 1 << s, 64);

    out[((size_t)b * NN + i0) * ND + lane] = accf[0] * RCPF(dn);
}

extern "C" void kernel_launch(void* const* d_in, const int* in_sizes, int n_in,
                              void* d_out, int out_size, void* d_ws, size_t ws_size,
                              hipStream_t stream) {
    const float* x = (const float*)d_in[0];
    float* out = (float*)d_out;
    dim3 grid(NB * (NN / TI));   // 1024 workgroups
    dim3 block(256);
    addattn_kernel<<<grid, block, 0, stream>>>(x, out);
}

// Round 14
// 74.609 us; speedup vs baseline: 1.3665x; 1.3665x over previous
//
#include <hip/hip_runtime.h>

// AdditiveSelfAttentionLayer: B=4, N=1024, D=64, fp32
// out[b,i,d] = sum_j softmax_j( sum_d' tanh(x[b,i,d']+x[b,j,d']) ) * x[b,j,d]
//
// Identities:
//   tanh(s) = 1 - 2/(1+e^{2s});  e_j = sum_d tanh = 64 - 2*rsum
//   e^{2s} = E_i[d]*E_j[d],  E = exp2(C*x), C = 2*log2(e)   (E precomputed once)
//   PAIR MERGE: 1/(1+a)+1/(1+b) = (2+p)/(1+p+q), p=a+b, q=ab  (native v2f pk ops)
//   softmax shift 32: w_j = exp(e_j - 32) = exp2(32*log2e - C*rsum_j)
//
// Round 14: R7 (65us; VGPR=64 + acc in AGPRs, zero scratch) with IPW=2:
// each wave computes TWO i-rows, so every LDS b128 read (Ej, xj), staging op,
// barrier, and address calc serves 2 rows (per-row LDS 40 -> 20 ops).
// Lessons applied: no px prefetch array (R13: PromoteAlloca moved it to LDS
// -> 9.2M bank conflicts; R9/10/12: scratch spill), no asm pins, no
// waves_per_eu — identical codegen conditions to R7, which allocated the
// big accumulators to AGPRs for free.

#define NB 4
#define NN 1024
#define ND 64
#define TJ 64             // j-rows per LDS tile (lane = local j)
#define TI 8              // i-rows per WG (4 waves x 2 rows)
#define NTILES (NN / TJ)  // 16

#if __has_builtin(__builtin_amdgcn_exp2f)
#define EXP2F(x) __builtin_amdgcn_exp2f(x)
#else
#define EXP2F(x) exp2f(x)
#endif
#if __has_builtin(__builtin_amdgcn_rcpf)
#define RCPF(x) __builtin_amdgcn_rcpf(x)
#else
#define RCPF(x) (1.0f / (x))
#endif

static constexpr float C_SCALE = 2.8853900817779268f;   // 2*log2(e)
static constexpr float K_SHIFT = 46.166241308446828f;   // 32*log2(e)

typedef float v2f __attribute__((ext_vector_type(2)));

#define PKFMA(a, b, c) __builtin_elementwise_fma((a), (b), (c))

__device__ __forceinline__ v2f vlo(float4 v) { v2f r; r.x = v.x; r.y = v.y; return r; }
__device__ __forceinline__ v2f vhi(float4 v) { v2f r; r.x = v.z; r.y = v.w; return r; }

// prep: E[i] = exp2(C * x[i]) for all B*N*D elements
__global__ __launch_bounds__(256) void prep_kernel(const float* __restrict__ x,
                                                   float* __restrict__ E) {
    int idx = blockIdx.x * 256 + threadIdx.x;
    float4 v = ((const float4*)x)[idx];
    float4 e;
    e.x = EXP2F(C_SCALE * v.x);
    e.y = EXP2F(C_SCALE * v.y);
    e.z = EXP2F(C_SCALE * v.z);
    e.w = EXP2F(C_SCALE * v.w);
    ((float4*)E)[idx] = e;
}

template <bool HAS_E>
__global__ __launch_bounds__(256, 2) void addattn_kernel(const float* __restrict__ x,
                                                         const float* __restrict__ E,
                                                         float* __restrict__ out) {
    __shared__ float E_lds[TJ * ND];   // 16 KB, XOR-swizzled at float4 grain
    __shared__ float x_lds[TJ * ND];   // 16 KB, same swizzle

    const int tid   = threadIdx.x;
    const int lane  = tid & 63;
    const int wave  = tid >> 6;
    const int wg    = blockIdx.x;
    const int b     = wg >> 7;                       // 128 WGs per batch
    const int ibase = (wg & 127) * TI;
    // wave-uniform i-row indices (SGPR -> Ei loads become s_loads)
    const int i0    = __builtin_amdgcn_readfirstlane(ibase + wave * 2);
    const int i1    = i0 + 1;

    const float* xb   = x + (size_t)b * NN * ND;
    const float* Eb   = E + (size_t)b * NN * ND;
    const float* Eip0 = Eb + (size_t)i0 * ND;        // uniform pointers
    const float* Eip1 = Eb + (size_t)i1 * ND;
    const float* xip0 = xb + (size_t)i0 * ND;        // fallback path
    const float* xip1 = xb + (size_t)i1 * ND;

    v2f acc0[32];                       // out[i0] numerator, d-pairs, in-lane
    v2f acc1[32];                       // out[i1]
    #pragma unroll
    for (int k = 0; k < 32; ++k) { acc0[k] = (v2f){0.f, 0.f}; acc1[k] = (v2f){0.f, 0.f}; }
    float dn0 = 0.f, dn1 = 0.f;         // per-lane denominator partials

    for (int t = 0; t < NTILES; ++t) {
        __syncthreads();   // protect LDS from previous tile's readers
        {
            const float4* srcx = (const float4*)(xb + (size_t)t * TJ * ND);
            const float4* srcE = (const float4*)(Eb + (size_t)t * TJ * ND);
            #pragma unroll
            for (int it = 0; it < 4; ++it) {
                int idx = it * 256 + tid;
                int j   = idx >> 4;         // 16 float4 per row
                int c   = idx & 15;
                int wof = j * ND + ((c ^ (j & 15)) << 2);
                float4 xv = srcx[idx];
                *(float4*)&x_lds[wof] = xv;
                float4 ev;
                if (HAS_E) {
                    ev = srcE[idx];
                } else {
                    ev.x = EXP2F(C_SCALE * xv.x);
                    ev.y = EXP2F(C_SCALE * xv.y);
                    ev.z = EXP2F(C_SCALE * xv.z);
                    ev.w = EXP2F(C_SCALE * xv.w);
                }
                *(float4*)&E_lds[wof] = ev;
            }
        }
        __syncthreads();

        // ---- tanh phase: lane = local j; 2 i-rows; pair-merged packed rcp ----
        const int key = lane & 15;
        v2f rs0e = {0.f, 0.f}, rs0o = {0.f, 0.f};
        v2f rs1e = {0.f, 0.f}, rs1o = {0.f, 0.f};
        #pragma unroll
        for (int c = 0; c < 16; ++c) {
            float4 ejq = *(const float4*)&E_lds[lane * ND + ((c ^ key) << 2)];
            v2f ej_lo = vlo(ejq), ej_hi = vhi(ejq);
            v2f e0l, e0h, e1l, e1h;
            if (HAS_E) {
                float4 e0q = *(const float4*)&Eip0[c * 4];   // scalar s_load
                float4 e1q = *(const float4*)&Eip1[c * 4];
                e0l = vlo(e0q); e0h = vhi(e0q);
                e1l = vlo(e1q); e1h = vhi(e1q);
            } else {
                float4 x0q = *(const float4*)&xip0[c * 4];
                float4 x1q = *(const float4*)&xip1[c * 4];
                e0l.x = EXP2F(C_SCALE * x0q.x); e0l.y = EXP2F(C_SCALE * x0q.y);
                e0h.x = EXP2F(C_SCALE * x0q.z); e0h.y = EXP2F(C_SCALE * x0q.w);
                e1l.x = EXP2F(C_SCALE * x1q.x); e1l.y = EXP2F(C_SCALE * x1q.y);
                e1h.x = EXP2F(C_SCALE * x1q.z); e1h.y = EXP2F(C_SCALE * x1q.w);
            }
            {
                v2f a = e0l * ej_lo;
                v2f q = e0h * ej_hi;
                v2f p = a + q;
                v2f r = PKFMA(a, q, p + 1.0f);              // 1 + p + q
                v2f tt; tt.x = RCPF(r.x); tt.y = RCPF(r.y);
                if (c & 1) rs0o = PKFMA(p + 2.0f, tt, rs0o);
                else       rs0e = PKFMA(p + 2.0f, tt, rs0e);
            }
            {
                v2f a = e1l * ej_lo;
                v2f q = e1h * ej_hi;
                v2f p = a + q;
                v2f r = PKFMA(a, q, p + 1.0f);
                v2f tt; tt.x = RCPF(r.x); tt.y = RCPF(r.y);
                if (c & 1) rs1o = PKFMA(p + 2.0f, tt, rs1o);
                else       rs1e = PKFMA(p + 2.0f, tt, rs1e);
            }
        }
        v2f rs0 = rs0e + rs0o;
        v2f rs1 = rs1e + rs1o;
        float w0 = EXP2F(fmaf(-C_SCALE, rs0.x + rs0.y, K_SHIFT));  // exp(e_j - 32)
        float w1 = EXP2F(fmaf(-C_SCALE, rs1.x + rs1.y, K_SHIFT));
        dn0 += w0;
        dn1 += w1;
        v2f w20; w20.x = w0; w20.y = w0;
        v2f w21; w21.x = w1; w21.y = w1;

        // ---- PV phase: one x read serves both rows ----
        #pragma unroll
        for (int c = 0; c < 16; ++c) {
            float4 xq = *(const float4*)&x_lds[lane * ND + ((c ^ key) << 2)];
            v2f xl = vlo(xq), xh = vhi(xq);
            acc0[2 * c]     = PKFMA(w20, xl, acc0[2 * c]);
            acc0[2 * c + 1] = PKFMA(w20, xh, acc0[2 * c + 1]);
            acc1[2 * c]     = PKFMA(w21, xl, acc1[2 * c]);
            acc1[2 * c + 1] = PKFMA(w21, xh, acc1[2 * c + 1]);
        }
    }

    // ---- cross-lane transpose-reduction (round-1/7-verified butterfly), x2 ----
    float* accf0 = (float*)acc0;
    float* accf1 = (float*)acc1;
    #pragma unroll
    for (int s = 0; s < 6; ++s) {
        const int half = 32 >> s;
        const int sel  = (lane >> (5 - s)) & 1;
        #pragma unroll
        for (int k = 0; k < half; ++k) {
            {
                float keep = sel ? accf0[k + half] : accf0[k];
                float send = sel ? accf0[k] : accf0[k + half];
                float recv = __shfl_xor(send, half, 64);
                accf0[k] = keep + recv;
            }
            {
                float keep = sel ? accf1[k + half] : accf1[k];
                float send = sel ? accf1[k] : accf1[k + half];
                float recv = __shfl_xor(send, half, 64);
                accf1[k] = keep + recv;
            }
        }
    }
    #pragma unroll
    for (int s = 0; s < 6; ++s) {
        dn0 += __shfl_xor(dn0, 1 << s, 64);
        dn1 += __shfl_xor(dn1, 1 << s, 64);
    }

    out[((size_t)b * NN + i0) * ND + lane] = accf0[0] * RCPF(dn0);
    out[((size_t)b * NN + i1) * ND + lane] = accf1[0] * RCPF(dn1);
}

extern "C" void kernel_launch(void* const* d_in, const int* in_sizes, int n_in,
                              void* d_out, int out_size, void* d_ws, size_t ws_size,
                              hipStream_t stream) {
    const float* x = (const float*)d_in[0];
    float* out = (float*)d_out;
    const size_t e_bytes = (size_t)NB * NN * ND * sizeof(float);   // 1 MB

    dim3 grid(NB * (NN / TI));   // 512 workgroups
    dim3 block(256);

    if (ws_size >= e_bytes) {
        float* E = (float*)d_ws;
        prep_kernel<<<dim3(NB * NN * ND / 4 / 256), dim3(256), 0, stream>>>(x, E);
        addattn_kernel<true><<<grid, block, 0, stream>>>(x, E, out);
    } else {
        addattn_kernel<false><<<grid, block, 0, stream>>>(x, (const float*)nullptr, out);
    }
}